// Round 5
// baseline (352.465 us; speedup 1.0000x reference)
//
#include <hip/hip_runtime.h>
#include <math.h>

#define BLOCK 512
#define MSTR 209   // mags row stride (f32): 209 mod 32 = 17, coprime -> conflict-free

typedef __attribute__((ext_vector_type(8))) short short8;
typedef __attribute__((ext_vector_type(16))) float f32x16;
typedef __attribute__((ext_vector_type(4))) unsigned uint4v;

__device__ inline unsigned short f2bf(float x) {
    unsigned u = __float_as_uint(x);
    unsigned r = u + 0x7fffu + ((u >> 16) & 1u);
    return (unsigned short)(r >> 16);
}

__device__ inline void splitA(const float* v, short8& Ah, short8& Al) {
    uint4v ah, al;
    #pragma unroll
    for (int q = 0; q < 4; ++q) {
        unsigned short h0 = f2bf(v[2*q]),   h1 = f2bf(v[2*q+1]);
        float hf0 = __uint_as_float((unsigned)h0 << 16);
        float hf1 = __uint_as_float((unsigned)h1 << 16);
        unsigned short l0 = f2bf(v[2*q] - hf0), l1 = f2bf(v[2*q+1] - hf1);
        ah[q] = (unsigned)h0 | ((unsigned)h1 << 16);
        al[q] = (unsigned)l0 | ((unsigned)l1 << 16);
    }
    Ah = __builtin_bit_cast(short8, ah);
    Al = __builtin_bit_cast(short8, al);
}

// issue A loads for chunk kc into d0/d1 (s=0/1); reflect handled on edge rows
__device__ inline void loadA(const float* __restrict__ x, int te, int kc, int g,
                             float* d0, float* d1) {
    #pragma unroll
    for (int s = 0; s < 2; ++s) {
        float* d = s ? d1 : d0;
        int i0 = 160 * te - 200 + kc * 32 + s * 16 + g * 8;
        if (i0 >= 0 && i0 <= 15992) {
            float4 a0 = *(const float4*)(x + i0);
            float4 a1 = *(const float4*)(x + i0 + 4);
            d[0] = a0.x; d[1] = a0.y; d[2] = a0.z; d[3] = a0.w;
            d[4] = a1.x; d[5] = a1.y; d[6] = a1.z; d[7] = a1.w;
        } else {
            #pragma unroll
            for (int e = 0; e < 8; ++e) {
                int p = i0 + e;
                p = (p < 0) ? -p : p;
                p = (p > 15999) ? (31998 - p) : p;
                d[e] = x[p];
            }
        }
    }
}

// ---------------------------------------------------------------------------
// Kernel 1: filters output (64 x 201) -> tail of d_out. Mirrors _get_filters.
// ---------------------------------------------------------------------------
__global__ void fse_filters(const float* __restrict__ low_hz_,
                            const float* __restrict__ band_hz_,
                            float* __restrict__ out)
{
    int idx = blockIdx.x * 256 + threadIdx.x;
    if (idx >= 64 * 201) return;
    int c = idx / 201;
    int k = idx - c * 201;
    float lo = 50.0f + fabsf(low_hz_[c]);
    float hi = lo + 50.0f + fabsf(band_hz_[c]);
    hi = fminf(fmaxf(hi, 50.0f), 8000.0f);
    float ctr = 0.5f * (lo + hi);
    float hbw = 0.5f * (hi - lo);
    float fq = 40.0f * (float)k;
    float resp = 1.0f - fabsf(fq - ctr) / hbw;
    out[idx] = (fq >= lo && fq <= hi) ? resp : 0.0f;
}

// ---------------------------------------------------------------------------
// Kernel 1b: B in chunk-linear layout: Bt[kc][pl][part][row][8] bf16 (hi/lo).
// ---------------------------------------------------------------------------
__global__ void fse_setup_B(unsigned short* __restrict__ bt)
{
    int idx = blockIdx.x * 256 + threadIdx.x;   // 13*2*4*448*8 = 372736
    if (idx >= 372736) return;
    int e   = idx & 7;
    int t   = idx >> 3;
    int row = t % 448;
    int q   = t / 448;          // ((kc*2 + pl)*4 + p)
    int p   = q & 3;
    int pl  = (q >> 2) & 1;
    int kc  = q >> 3;
    int n   = kc * 32 + p * 8 + e;
    float v = 0.0f;
    if (n < 400) {
        int bin = -1, isim = 0;
        if (row <= 200) bin = row;
        else if (row >= 224 && row <= 424) { bin = row - 224; isim = 1; }
        if (bin >= 0) {
            int a = (bin * n) % 400;            // exact integer phase reduction
            float th = 6.283185307179586f * ((float)a / 400.0f);
            float sn, cs;
            sincosf(th, &sn, &cs);
            float wn = 0.5f - 0.5f * cosf(6.283185307179586f * ((float)n / 400.0f));
            v = isim ? (-wn * sn) : (wn * cs);
        }
    }
    unsigned short h = f2bf(v);
    float hf = __uint_as_float((unsigned)h << 16);
    unsigned short l = f2bf(v - hf);
    bt[idx] = pl ? l : h;
}

// ---------------------------------------------------------------------------
// Kernel 2 (MFMA path): one block per batch item.
//  C[128 x 448] = A[128 x 416] x B[416 x 448], split-2 bf16 (3 products).
//  R5: A software-pipelined one kc ahead in registers (B prefetch issued
//  FIRST, A second; A consumed only after the next barrier -> no per-kc
//  vmcnt serialization). Filterbank re-laid out lane=t (uniform k-loop,
//  conflict-free stride-209 mags). One-pass LN.
// ---------------------------------------------------------------------------
__global__ __launch_bounds__(512, 2)
void fse_main_mfma(const float* __restrict__ wav,
                   const float* __restrict__ low_hz_,
                   const float* __restrict__ band_hz_,
                   const float* __restrict__ ln_w,
                   const float* __restrict__ ln_b,
                   const unsigned short* __restrict__ Bt,
                   float* __restrict__ out)
{
    // GEMM phase: [0,57344) buf0 | [57344,114688) buf1
    // post phase: [0, 84436) mags[101][209] f32 | [84544, 110400) fbuf[64*101]
    __shared__ __align__(16) char smem[114688];
    float* mags = (float*)smem;
    float* fbuf = (float*)(smem + 84544);

    __shared__ float fctr[64], finv[64];
    __shared__ int   fks[64], fke[64];
    __shared__ float red[16];
    __shared__ float stats[2];

    const int b    = blockIdx.x;
    const int tid  = threadIdx.x;
    const int w    = tid >> 6;
    const int lane = tid & 63;
    const float* __restrict__ x = wav + b * 16000;

    // ---- per-channel filter params
    if (tid < 64) {
        float lo = 50.0f + fabsf(low_hz_[tid]);
        float hi = lo + 50.0f + fabsf(band_hz_[tid]);
        hi = fminf(fmaxf(hi, 50.0f), 8000.0f);
        float ctr = 0.5f * (lo + hi);
        float hbw = 0.5f * (hi - lo);
        int ks = (int)ceilf(lo * 0.025f);
        if (ks < 0) ks = 0;
        while (40.0f * (float)ks < lo) ++ks;
        while (ks > 0 && 40.0f * (float)(ks - 1) >= lo) --ks;
        int ke = (int)floorf(hi * 0.025f);
        if (ke > 200) ke = 200;
        while (40.0f * (float)ke > hi) --ke;
        while (ke < 200 && 40.0f * (float)(ke + 1) <= hi) ++ke;
        fctr[tid] = ctr;
        finv[tid] = (hbw > 0.0f) ? (1.0f / hbw) : 0.0f;
        fks[tid]  = ks;
        fke[tid]  = ke;
    }

    const int mt   = w >> 1;          // m-tile: rows 32*mt .. 32*mt+31
    const int half = w & 1;           // 0: re cols, 1: im cols
    const int jrow = lane & 31;
    const int g    = lane >> 5;
    const int arow = mt * 32 + jrow;
    const int te   = (arow <= 100) ? arow : 50;   // discarded rows -> interior

    const uint4* __restrict__ btg = (const uint4*)Bt;   // 3584 uint4 per kc

    // ---- prologue: A(0) into regs; stage B(0) into buffer 0
    float ac[2][8], an[2][8];
    loadA(x, te, 0, g, ac[0], ac[1]);
    {
        uint4 rr[7];
        #pragma unroll
        for (int i = 0; i < 7; ++i) rr[i] = btg[i * 512 + tid];
        uint4* dst = (uint4*)smem;
        #pragma unroll
        for (int i = 0; i < 7; ++i) dst[i * 512 + tid] = rr[i];
    }
    __syncthreads();

    f32x16 acc[7];
    #pragma unroll
    for (int n = 0; n < 7; ++n) {
        #pragma unroll
        for (int e = 0; e < 16; ++e) acc[n][e] = 0.0f;
    }

    int curoff = 0;
    for (int kc = 0; kc < 13; ++kc) {
        const bool pre = (kc < 12);
        uint4 rr[7];
        if (pre) {
            // issue B(kc+1) FIRST, then A(kc+1): ds_write below waits only
            // for rr (vmcnt leaves A in flight); A consumed after barrier.
            const uint4* src = btg + (kc + 1) * 3584;
            #pragma unroll
            for (int i = 0; i < 7; ++i) rr[i] = src[i * 512 + tid];
            loadA(x, te, kc + 1, g, an[0], an[1]);
        }

        // split current A (registers only, no waits)
        short8 Ah[2], Al[2];
        splitA(ac[0], Ah[0], Al[0]);
        splitA(ac[1], Ah[1], Al[1]);

        const unsigned short* bs = (const unsigned short*)(smem + curoff);
        #pragma unroll
        for (int s = 0; s < 2; ++s) {
            const int pb = (s * 2 + g) * 448;
            #pragma unroll
            for (int n = 0; n < 7; ++n) {
                const int ro = (half * 7 + n) * 32 + jrow;
                short8 Bh = *(const short8*)(bs + (pb + ro) * 8);
                short8 Bl = *(const short8*)(bs + 14336 + (pb + ro) * 8);
                acc[n] = __builtin_amdgcn_mfma_f32_32x32x16_bf16(Ah[s], Bh, acc[n], 0, 0, 0);
                acc[n] = __builtin_amdgcn_mfma_f32_32x32x16_bf16(Ah[s], Bl, acc[n], 0, 0, 0);
                acc[n] = __builtin_amdgcn_mfma_f32_32x32x16_bf16(Al[s], Bh, acc[n], 0, 0, 0);
            }
        }

        if (pre) {
            uint4* dst = (uint4*)(smem + (curoff ^ 57344));
            #pragma unroll
            for (int i = 0; i < 7; ++i) dst[i * 512 + tid] = rr[i];
        }
        __syncthreads();
        if (pre) {
            #pragma unroll
            for (int i = 0; i < 8; ++i) { ac[0][i] = an[0][i]; ac[1][i] = an[1][i]; }
        }
        curoff ^= 57344;
    }

    // ---- epilogue: re waves write C_re; im waves fold sqrt(re^2+im^2)
    if (half == 0) {
        #pragma unroll
        for (int n = 0; n < 7; ++n) {
            int k = n * 32 + jrow;
            if (k <= 200) {
                #pragma unroll
                for (int r = 0; r < 16; ++r) {
                    int t = mt * 32 + (r & 3) + 8 * (r >> 2) + 4 * g;
                    if (t <= 100) mags[t * MSTR + k] = acc[n][r];
                }
            }
        }
    }
    __syncthreads();
    if (half == 1) {
        #pragma unroll
        for (int n = 0; n < 7; ++n) {
            int k = n * 32 + jrow;
            if (k <= 200) {
                #pragma unroll
                for (int r = 0; r < 16; ++r) {
                    int t = mt * 32 + (r & 3) + 8 * (r >> 2) + 4 * g;
                    if (t <= 100) {
                        float re = mags[t * MSTR + k];
                        float im = acc[n][r];
                        mags[t * MSTR + k] = sqrtf(re * re + im * im);
                    }
                }
            }
        }
    }
    __syncthreads();

    // ---- filterbank: lane = t (wave-uniform k-loop, conflict-free reads)
    {
        const int t0 = lane;
        const int t1v = 64 + lane;
        const int t1 = (t1v <= 100) ? t1v : 100;   // clamped read, guarded store
        #pragma unroll
        for (int i = 0; i < 8; ++i) {
            const int c = w * 8 + i;
            const float ctr = fctr[c];
            const float inv = finv[c];
            const int ks = fks[c], ke = fke[c];
            float a0 = 0.0f, a1 = 0.0f;
            for (int k = ks; k <= ke; ++k) {
                float resp = 1.0f - fabsf(40.0f * (float)k - ctr) * inv;
                a0 = fmaf(resp, mags[t0 * MSTR + k], a0);
                a1 = fmaf(resp, mags[t1 * MSTR + k], a1);
            }
            fbuf[c * 101 + t0] = a0;
            if (t1v <= 100) fbuf[c * 101 + t1v] = a1;
        }
    }
    __syncthreads();

    // ---- global LayerNorm (one-pass: sum + sumsq)
    float s = 0.0f, ss = 0.0f;
    for (int i = tid; i < 6464; i += BLOCK) {
        float vv = fbuf[i];
        s += vv;
        ss = fmaf(vv, vv, ss);
    }
    #pragma unroll
    for (int off = 32; off > 0; off >>= 1) {
        s  += __shfl_down(s,  off, 64);
        ss += __shfl_down(ss, off, 64);
    }
    if (lane == 0) { red[w] = s; red[8 + w] = ss; }
    __syncthreads();
    if (tid == 0) {
        float ts = 0.0f, tss = 0.0f;
        for (int i = 0; i < 8; ++i) { ts += red[i]; tss += red[8 + i]; }
        float mu = ts * (1.0f / 6464.0f);
        stats[0] = mu;
        stats[1] = tss * (1.0f / 6464.0f) - mu * mu;
    }
    __syncthreads();
    const float mu   = stats[0];
    const float isig = 1.0f / sqrtf(stats[1] + 1e-5f);

    // ---- log-energy + interp 101->64 + transposed store
    for (int idx = tid; idx < 4096; idx += BLOCK) {
        const int to = idx >> 6;
        const int c  = idx & 63;
        float pos = ((float)to + 0.5f) * 1.578125f - 0.5f;
        pos = fminf(fmaxf(pos, 0.0f), 100.0f);
        int i0 = (int)floorf(pos);
        int i1 = i0 + 1; if (i1 > 100) i1 = 100;
        float fr = pos - (float)i0;
        float wc = ln_w[c], bc = ln_b[c];
        float x0 = fbuf[c * 101 + i0];
        float x1 = fbuf[c * 101 + i1];
        float y0 = fmaf(wc, (x0 - mu) * isig, bc);
        float y1 = fmaf(wc, (x1 - mu) * isig, bc);
        float l0 = log10f(fmaf(y0, y0, 1e-6f));
        float l1 = log10f(fmaf(y1, y1, 1e-6f));
        out[b * 4096 + idx] = l0 * (1.0f - fr) + l1 * fr;
    }
}

// ---------------------------------------------------------------------------
// Fallback (R2 VALU path) if ws_size is too small for the B table.
// ---------------------------------------------------------------------------
__global__ __launch_bounds__(512, 2)
void fse_main_valu(const float* __restrict__ wav,
                   const float* __restrict__ low_hz_,
                   const float* __restrict__ band_hz_,
                   const float* __restrict__ ln_w,
                   const float* __restrict__ ln_b,
                   float* __restrict__ out)
{
    __shared__ float  xp[16400];
    __shared__ float2 Xs[8][204];
    __shared__ float  mags[8][204];
    __shared__ float  fbuf[64 * 101];
    __shared__ float  fctr[64], finv[64];
    __shared__ int    fks[64], fke[64];
    __shared__ float  red[8];
    __shared__ float  stats[2];

    const int b    = blockIdx.x;
    const int tid  = threadIdx.x;
    const int w    = tid >> 6;
    const int lane = tid & 63;
    const float* __restrict__ x = wav + b * 16000;

    for (int i = tid; i < 16400; i += BLOCK) {
        int p = i - 200;
        p = (p < 0) ? -p : p;
        p = (p > 15999) ? (31998 - p) : p;
        xp[i] = x[p];
    }
    if (tid < 64) {
        float lo = 50.0f + fabsf(low_hz_[tid]);
        float hi = lo + 50.0f + fabsf(band_hz_[tid]);
        hi = fminf(fmaxf(hi, 50.0f), 8000.0f);
        float ctr = 0.5f * (lo + hi);
        float hbw = 0.5f * (hi - lo);
        int ks = (int)ceilf(lo * 0.025f);
        if (ks < 0) ks = 0;
        while (40.0f * (float)ks < lo) ++ks;
        while (ks > 0 && 40.0f * (float)(ks - 1) >= lo) --ks;
        int ke = (int)floorf(hi * 0.025f);
        if (ke > 200) ke = 200;
        while (40.0f * (float)ke > hi) --ke;
        while (ke < 200 && 40.0f * (float)(ke + 1) <= hi) ++ke;
        fctr[tid] = ctr;
        finv[tid] = (hbw > 0.0f) ? (1.0f / hbw) : 0.0f;
        fks[tid]  = ks;
        fke[tid]  = ke;
    }
    __syncthreads();

    const float cctr = fctr[lane];
    const float cinv = finv[lane];
    const int   cks  = fks[lane];
    const int   cke  = fke[lane];

    float reX[4][13], imX[4][13];
    const float2* __restrict__ xp2 = (const float2*)xp;
    float c0[4], s0[4], c1[4], s1[4], cd[4], sd[4];
    #pragma unroll
    for (int m = 0; m < 4; ++m) {
        const int k = m * 64 + lane;
        const float th = -0.015707963267948966f * (float)k;
        sincosf(th, &s1[m], &c1[m]);
        sincosf(th + th, &sd[m], &cd[m]);
        c0[m] = 1.0f; s0[m] = 0.0f;
        #pragma unroll
        for (int j = 0; j < 13; ++j) { reX[m][j] = 0.0f; imX[m][j] = 0.0f; }
    }
    const int o12 = (w < 5) ? 640 * 12 : 0;
    int ib = 80 * w;
    #pragma unroll 2
    for (int h = 0; h < 200; ++h) {
        #pragma unroll
        for (int j = 0; j < 13; ++j) {
            const int off = (j == 12) ? o12 : 640 * j;
            float2 f = xp2[ib + off];
            #pragma unroll
            for (int m = 0; m < 4; ++m) {
                reX[m][j] = fmaf(f.x, c0[m], reX[m][j]);
                imX[m][j] = fmaf(f.x, s0[m], imX[m][j]);
                reX[m][j] = fmaf(f.y, c1[m], reX[m][j]);
                imX[m][j] = fmaf(f.y, s1[m], imX[m][j]);
            }
        }
        #pragma unroll
        for (int m = 0; m < 4; ++m) {
            float nc0 = fmaf(c0[m], cd[m], -(s0[m] * sd[m]));
            float ns0 = fmaf(s0[m], cd[m],  (c0[m] * sd[m]));
            float nc1 = fmaf(c1[m], cd[m], -(s1[m] * sd[m]));
            float ns1 = fmaf(s1[m], cd[m],  (c1[m] * sd[m]));
            c0[m] = nc0; s0[m] = ns0; c1[m] = nc1; s1[m] = ns1;
        }
        ++ib;
    }

    float2* __restrict__ myX   = &Xs[w][0];
    float*  __restrict__ mymag = &mags[w][0];
    for (int j = 0; j < 13; ++j) {
        const int t = w + 8 * j;
        if (t > 100) break;
        #pragma unroll
        for (int m = 0; m < 4; ++m) {
            const int k = m * 64 + lane;
            if (k < 202) myX[k] = make_float2(reX[m][j], imX[m][j]);
        }
        asm volatile("s_waitcnt lgkmcnt(0)" ::: "memory");
        #pragma unroll
        for (int m = 0; m < 4; ++m) {
            const int k = m * 64 + lane;
            if (k <= 200) {
                float2 xm = (k == 0) ? myX[1] : myX[k - 1];
                float imm = (k == 0) ? -xm.y : xm.y;
                float2 xq = myX[k + 1];
                float rw = 0.5f * reX[m][j] - 0.25f * (xm.x + xq.x);
                float iw = 0.5f * imX[m][j] - 0.25f * (imm  + xq.y);
                mymag[k] = sqrtf(rw * rw + iw * iw);
            }
        }
        asm volatile("s_waitcnt lgkmcnt(0)" ::: "memory");
        float acc = 0.0f;
        for (int k = cks; k <= cke; ++k) {
            float resp = 1.0f - fabsf(40.0f * (float)k - cctr) * cinv;
            acc = fmaf(resp, mymag[k], acc);
        }
        fbuf[lane * 101 + t] = acc;
    }
    __syncthreads();

    float s = 0.0f;
    for (int i = tid; i < 6464; i += BLOCK) s += fbuf[i];
    #pragma unroll
    for (int off = 32; off > 0; off >>= 1) s += __shfl_down(s, off, 64);
    if (lane == 0) red[w] = s;
    __syncthreads();
    if (tid == 0) {
        float tsum = 0.0f;
        for (int i = 0; i < 8; ++i) tsum += red[i];
        stats[0] = tsum * (1.0f / 6464.0f);
    }
    __syncthreads();
    const float mu = stats[0];
    float v = 0.0f;
    for (int i = tid; i < 6464; i += BLOCK) { float d = fbuf[i] - mu; v = fmaf(d, d, v); }
    #pragma unroll
    for (int off = 32; off > 0; off >>= 1) v += __shfl_down(v, off, 64);
    if (lane == 0) red[w] = v;
    __syncthreads();
    if (tid == 0) {
        float tsum = 0.0f;
        for (int i = 0; i < 8; ++i) tsum += red[i];
        stats[1] = tsum * (1.0f / 6464.0f);
    }
    __syncthreads();
    const float var  = stats[1];
    const float isig = 1.0f / sqrtf(var + 1e-5f);

    for (int idx = tid; idx < 4096; idx += BLOCK) {
        const int to = idx >> 6;
        const int c  = idx & 63;
        float pos = ((float)to + 0.5f) * 1.578125f - 0.5f;
        pos = fminf(fmaxf(pos, 0.0f), 100.0f);
        int i0 = (int)floorf(pos);
        int i1 = i0 + 1; if (i1 > 100) i1 = 100;
        float fr = pos - (float)i0;
        float wc = ln_w[c], bc = ln_b[c];
        float x0 = fbuf[c * 101 + i0];
        float x1 = fbuf[c * 101 + i1];
        float y0 = fmaf(wc, (x0 - mu) * isig, bc);
        float y1 = fmaf(wc, (x1 - mu) * isig, bc);
        float l0 = log10f(fmaf(y0, y0, 1e-6f));
        float l1 = log10f(fmaf(y1, y1, 1e-6f));
        out[b * 4096 + idx] = l0 * (1.0f - fr) + l1 * fr;
    }
}

extern "C" void kernel_launch(void* const* d_in, const int* in_sizes, int n_in,
                              void* d_out, int out_size, void* d_ws, size_t ws_size,
                              hipStream_t stream)
{
    const float* wav = (const float*)d_in[0];
    const float* lo  = (const float*)d_in[1];
    const float* bd  = (const float*)d_in[2];
    const float* lw  = (const float*)d_in[3];
    const float* lb  = (const float*)d_in[4];
    float* out = (float*)d_out;

    fse_filters<<<(64 * 201 + 255) / 256, 256, 0, stream>>>(lo, bd, out + 1024 * 4096);

    const size_t BNEED = (size_t)372736 * sizeof(unsigned short); // 745472 B
    if (ws_size >= BNEED) {
        unsigned short* Bts = (unsigned short*)d_ws;
        fse_setup_B<<<(372736 + 255) / 256, 256, 0, stream>>>(Bts);
        fse_main_mfma<<<1024, BLOCK, 0, stream>>>(wav, lo, bd, lw, lb, Bts, out);
    } else {
        fse_main_valu<<<1024, BLOCK, 0, stream>>>(wav, lo, bd, lw, lb, out);
    }
}

// Round 6
// 231.663 us; speedup vs baseline: 1.5215x; 1.5215x over previous
//
#include <hip/hip_runtime.h>
#include <math.h>

#define BLOCK 512
#define MSTR 209   // mags row stride (f32): 209 mod 32 = 17, coprime -> conflict-free

typedef __attribute__((ext_vector_type(8))) short short8;
typedef __attribute__((ext_vector_type(16))) float f32x16;
typedef __attribute__((ext_vector_type(8))) float f32x8;

__device__ inline unsigned short f2bf(float x) {
    unsigned u = __float_as_uint(x);
    unsigned r = u + 0x7fffu + ((u >> 16) & 1u);
    return (unsigned short)(r >> 16);
}

struct ASplit { short8 h, l; };

// split 8 f32 (by value) into hi/lo bf16 fragments — pure register code
__device__ inline ASplit splitA(f32x8 v) {
    unsigned ah[4], al[4];
    #pragma unroll
    for (int q = 0; q < 4; ++q) {
        unsigned short h0 = f2bf(v[2*q]),   h1 = f2bf(v[2*q+1]);
        float hf0 = __uint_as_float((unsigned)h0 << 16);
        float hf1 = __uint_as_float((unsigned)h1 << 16);
        unsigned short l0 = f2bf(v[2*q] - hf0), l1 = f2bf(v[2*q+1] - hf1);
        ah[q] = (unsigned)h0 | ((unsigned)h1 << 16);
        al[q] = (unsigned)l0 | ((unsigned)l1 << 16);
    }
    ASplit r;
    r.h = __builtin_bit_cast(short8, *(uint4*)ah);
    r.l = __builtin_bit_cast(short8, *(uint4*)al);
    return r;
}

// load 8 consecutive floats at row-relative offset; reflect on edges; by value
__device__ inline f32x8 loadA8(const float* __restrict__ x, int i0) {
    f32x8 r;
    if (i0 >= 0 && i0 <= 15992) {
        float4 a0 = *(const float4*)(x + i0);
        float4 a1 = *(const float4*)(x + i0 + 4);
        r[0] = a0.x; r[1] = a0.y; r[2] = a0.z; r[3] = a0.w;
        r[4] = a1.x; r[5] = a1.y; r[6] = a1.z; r[7] = a1.w;
    } else {
        #pragma unroll
        for (int e = 0; e < 8; ++e) {
            int p = i0 + e;
            p = (p < 0) ? -p : p;
            p = (p > 15999) ? (31998 - p) : p;
            r[e] = x[p];
        }
    }
    return r;
}

// ---------------------------------------------------------------------------
// Kernel 1: filters output (64 x 201) -> tail of d_out. Mirrors _get_filters.
// ---------------------------------------------------------------------------
__global__ void fse_filters(const float* __restrict__ low_hz_,
                            const float* __restrict__ band_hz_,
                            float* __restrict__ out)
{
    int idx = blockIdx.x * 256 + threadIdx.x;
    if (idx >= 64 * 201) return;
    int c = idx / 201;
    int k = idx - c * 201;
    float lo = 50.0f + fabsf(low_hz_[c]);
    float hi = lo + 50.0f + fabsf(band_hz_[c]);
    hi = fminf(fmaxf(hi, 50.0f), 8000.0f);
    float ctr = 0.5f * (lo + hi);
    float hbw = 0.5f * (hi - lo);
    float fq = 40.0f * (float)k;
    float resp = 1.0f - fabsf(fq - ctr) / hbw;
    out[idx] = (fq >= lo && fq <= hi) ? resp : 0.0f;
}

// ---------------------------------------------------------------------------
// Kernel 1b: B in chunk-linear layout: Bt[kc][pl][part][row][8] bf16 (hi/lo).
// ---------------------------------------------------------------------------
__global__ void fse_setup_B(unsigned short* __restrict__ bt)
{
    int idx = blockIdx.x * 256 + threadIdx.x;   // 13*2*4*448*8 = 372736
    if (idx >= 372736) return;
    int e   = idx & 7;
    int t   = idx >> 3;
    int row = t % 448;
    int q   = t / 448;          // ((kc*2 + pl)*4 + p)
    int p   = q & 3;
    int pl  = (q >> 2) & 1;
    int kc  = q >> 3;
    int n   = kc * 32 + p * 8 + e;
    float v = 0.0f;
    if (n < 400) {
        int bin = -1, isim = 0;
        if (row <= 200) bin = row;
        else if (row >= 224 && row <= 424) { bin = row - 224; isim = 1; }
        if (bin >= 0) {
            int a = (bin * n) % 400;            // exact integer phase reduction
            float th = 6.283185307179586f * ((float)a / 400.0f);
            float sn, cs;
            sincosf(th, &sn, &cs);
            float wn = 0.5f - 0.5f * cosf(6.283185307179586f * ((float)n / 400.0f));
            v = isim ? (-wn * sn) : (wn * cs);
        }
    }
    unsigned short h = f2bf(v);
    float hf = __uint_as_float((unsigned)h << 16);
    unsigned short l = f2bf(v - hf);
    bt[idx] = pl ? l : h;
}

// ---------------------------------------------------------------------------
// Kernel 2 (MFMA path): one block per batch item.
//  C[128 x 448] = A[128 x 416] x B[416 x 448], split-2 bf16 (3 products).
//  R6 = R5 schedule with ALL A-state in value-semantic ext_vectors (no local
//  array ever has its address taken -> full SROA, zero scratch).
//  Per kc: issue B(kc+1) loads, then A(kc+1) loads; compute on current A/B;
//  ds_write B(kc+1) (waits only B); barrier; roll A regs.
// ---------------------------------------------------------------------------
__global__ __launch_bounds__(512, 2)
void fse_main_mfma(const float* __restrict__ wav,
                   const float* __restrict__ low_hz_,
                   const float* __restrict__ band_hz_,
                   const float* __restrict__ ln_w,
                   const float* __restrict__ ln_b,
                   const unsigned short* __restrict__ Bt,
                   float* __restrict__ out)
{
    // GEMM phase: [0,57344) buf0 | [57344,114688) buf1
    // post phase: [0, 84436) mags[101][209] f32 | [84544, 110400) fbuf[64*101]
    __shared__ __align__(16) char smem[114688];
    float* mags = (float*)smem;
    float* fbuf = (float*)(smem + 84544);

    __shared__ float fctr[64], finv[64];
    __shared__ int   fks[64], fke[64];
    __shared__ float red[16];
    __shared__ float stats[2];

    const int b    = blockIdx.x;
    const int tid  = threadIdx.x;
    const int w    = tid >> 6;
    const int lane = tid & 63;
    const float* __restrict__ x = wav + b * 16000;

    // ---- per-channel filter params
    if (tid < 64) {
        float lo = 50.0f + fabsf(low_hz_[tid]);
        float hi = lo + 50.0f + fabsf(band_hz_[tid]);
        hi = fminf(fmaxf(hi, 50.0f), 8000.0f);
        float ctr = 0.5f * (lo + hi);
        float hbw = 0.5f * (hi - lo);
        int ks = (int)ceilf(lo * 0.025f);
        if (ks < 0) ks = 0;
        while (40.0f * (float)ks < lo) ++ks;
        while (ks > 0 && 40.0f * (float)(ks - 1) >= lo) --ks;
        int ke = (int)floorf(hi * 0.025f);
        if (ke > 200) ke = 200;
        while (40.0f * (float)ke > hi) --ke;
        while (ke < 200 && 40.0f * (float)(ke + 1) <= hi) ++ke;
        fctr[tid] = ctr;
        finv[tid] = (hbw > 0.0f) ? (1.0f / hbw) : 0.0f;
        fks[tid]  = ks;
        fke[tid]  = ke;
    }

    const int mt   = w >> 1;          // m-tile: rows 32*mt .. 32*mt+31
    const int half = w & 1;           // 0: re cols, 1: im cols
    const int jrow = lane & 31;
    const int g    = lane >> 5;
    const int arow = mt * 32 + jrow;
    const int te   = (arow <= 100) ? arow : 50;   // discarded rows -> interior
    const int abase = 160 * te - 200 + g * 8;     // + kc*32 + s*16

    const uint4* __restrict__ btg = (const uint4*)Bt;   // 3584 uint4 per kc

    // ---- prologue: A(0) into regs; stage B(0) into buffer 0
    f32x8 ac0 = loadA8(x, abase);
    f32x8 ac1 = loadA8(x, abase + 16);
    {
        uint4 rr0 = btg[0 * 512 + tid], rr1 = btg[1 * 512 + tid];
        uint4 rr2 = btg[2 * 512 + tid], rr3 = btg[3 * 512 + tid];
        uint4 rr4 = btg[4 * 512 + tid], rr5 = btg[5 * 512 + tid];
        uint4 rr6 = btg[6 * 512 + tid];
        uint4* dst = (uint4*)smem;
        dst[0 * 512 + tid] = rr0; dst[1 * 512 + tid] = rr1;
        dst[2 * 512 + tid] = rr2; dst[3 * 512 + tid] = rr3;
        dst[4 * 512 + tid] = rr4; dst[5 * 512 + tid] = rr5;
        dst[6 * 512 + tid] = rr6;
    }
    __syncthreads();

    f32x16 acc[7];
    #pragma unroll
    for (int n = 0; n < 7; ++n) {
        #pragma unroll
        for (int e = 0; e < 16; ++e) acc[n][e] = 0.0f;
    }

    int curoff = 0;
    for (int kc = 0; kc < 13; ++kc) {
        const bool pre = (kc < 12);
        uint4 rr0, rr1, rr2, rr3, rr4, rr5, rr6;
        f32x8 an0, an1;
        if (pre) {
            // B(kc+1) issued FIRST, A(kc+1) second: the ds_write below only
            // drains B (vmcnt(2) leaves A in flight); A is consumed after
            // the barrier, its wait overlaps MFMA + ds_write + barrier.
            const uint4* src = btg + (kc + 1) * 3584;
            rr0 = src[0 * 512 + tid]; rr1 = src[1 * 512 + tid];
            rr2 = src[2 * 512 + tid]; rr3 = src[3 * 512 + tid];
            rr4 = src[4 * 512 + tid]; rr5 = src[5 * 512 + tid];
            rr6 = src[6 * 512 + tid];
            an0 = loadA8(x, abase + (kc + 1) * 32);
            an1 = loadA8(x, abase + (kc + 1) * 32 + 16);
        }

        // split current A (registers only)
        ASplit A0 = splitA(ac0);
        ASplit A1 = splitA(ac1);

        const unsigned short* bs = (const unsigned short*)(smem + curoff);
        #pragma unroll
        for (int s = 0; s < 2; ++s) {
            const short8 Ah = s ? A1.h : A0.h;
            const short8 Al = s ? A1.l : A0.l;
            const int pb = (s * 2 + g) * 448;
            #pragma unroll
            for (int n = 0; n < 7; ++n) {
                const int ro = (half * 7 + n) * 32 + jrow;
                short8 Bh = *(const short8*)(bs + (pb + ro) * 8);
                short8 Bl = *(const short8*)(bs + 14336 + (pb + ro) * 8);
                acc[n] = __builtin_amdgcn_mfma_f32_32x32x16_bf16(Ah, Bh, acc[n], 0, 0, 0);
                acc[n] = __builtin_amdgcn_mfma_f32_32x32x16_bf16(Ah, Bl, acc[n], 0, 0, 0);
                acc[n] = __builtin_amdgcn_mfma_f32_32x32x16_bf16(Al, Bh, acc[n], 0, 0, 0);
            }
        }

        if (pre) {
            uint4* dst = (uint4*)(smem + (curoff ^ 57344));
            dst[0 * 512 + tid] = rr0; dst[1 * 512 + tid] = rr1;
            dst[2 * 512 + tid] = rr2; dst[3 * 512 + tid] = rr3;
            dst[4 * 512 + tid] = rr4; dst[5 * 512 + tid] = rr5;
            dst[6 * 512 + tid] = rr6;
        }
        __syncthreads();
        if (pre) { ac0 = an0; ac1 = an1; }
        curoff ^= 57344;
    }

    // ---- epilogue: re waves write C_re; im waves fold sqrt(re^2+im^2)
    if (half == 0) {
        #pragma unroll
        for (int n = 0; n < 7; ++n) {
            int k = n * 32 + jrow;
            if (k <= 200) {
                #pragma unroll
                for (int r = 0; r < 16; ++r) {
                    int t = mt * 32 + (r & 3) + 8 * (r >> 2) + 4 * g;
                    if (t <= 100) mags[t * MSTR + k] = acc[n][r];
                }
            }
        }
    }
    __syncthreads();
    if (half == 1) {
        #pragma unroll
        for (int n = 0; n < 7; ++n) {
            int k = n * 32 + jrow;
            if (k <= 200) {
                #pragma unroll
                for (int r = 0; r < 16; ++r) {
                    int t = mt * 32 + (r & 3) + 8 * (r >> 2) + 4 * g;
                    if (t <= 100) {
                        float re = mags[t * MSTR + k];
                        float im = acc[n][r];
                        mags[t * MSTR + k] = sqrtf(re * re + im * im);
                    }
                }
            }
        }
    }
    __syncthreads();

    // ---- filterbank: lane = t (wave-uniform k-loop, conflict-free reads)
    {
        const int t0 = lane;
        const int t1v = 64 + lane;
        const int t1 = (t1v <= 100) ? t1v : 100;   // clamped read, guarded store
        #pragma unroll
        for (int i = 0; i < 8; ++i) {
            const int c = w * 8 + i;
            const float ctr = fctr[c];
            const float inv = finv[c];
            const int ks = fks[c], ke = fke[c];
            float a0 = 0.0f, a1 = 0.0f;
            for (int k = ks; k <= ke; ++k) {
                float resp = 1.0f - fabsf(40.0f * (float)k - ctr) * inv;
                a0 = fmaf(resp, mags[t0 * MSTR + k], a0);
                a1 = fmaf(resp, mags[t1 * MSTR + k], a1);
            }
            fbuf[c * 101 + t0] = a0;
            if (t1v <= 100) fbuf[c * 101 + t1v] = a1;
        }
    }
    __syncthreads();

    // ---- global LayerNorm (one-pass: sum + sumsq)
    float s = 0.0f, ss = 0.0f;
    for (int i = tid; i < 6464; i += BLOCK) {
        float vv = fbuf[i];
        s += vv;
        ss = fmaf(vv, vv, ss);
    }
    #pragma unroll
    for (int off = 32; off > 0; off >>= 1) {
        s  += __shfl_down(s,  off, 64);
        ss += __shfl_down(ss, off, 64);
    }
    if (lane == 0) { red[w] = s; red[8 + w] = ss; }
    __syncthreads();
    if (tid == 0) {
        float ts = 0.0f, tss = 0.0f;
        for (int i = 0; i < 8; ++i) { ts += red[i]; tss += red[8 + i]; }
        float mu = ts * (1.0f / 6464.0f);
        stats[0] = mu;
        stats[1] = tss * (1.0f / 6464.0f) - mu * mu;
    }
    __syncthreads();
    const float mu   = stats[0];
    const float isig = 1.0f / sqrtf(stats[1] + 1e-5f);

    // ---- log-energy + interp 101->64 + transposed store
    for (int idx = tid; idx < 4096; idx += BLOCK) {
        const int to = idx >> 6;
        const int c  = idx & 63;
        float pos = ((float)to + 0.5f) * 1.578125f - 0.5f;
        pos = fminf(fmaxf(pos, 0.0f), 100.0f);
        int i0 = (int)floorf(pos);
        int i1 = i0 + 1; if (i1 > 100) i1 = 100;
        float fr = pos - (float)i0;
        float wc = ln_w[c], bc = ln_b[c];
        float x0 = fbuf[c * 101 + i0];
        float x1 = fbuf[c * 101 + i1];
        float y0 = fmaf(wc, (x0 - mu) * isig, bc);
        float y1 = fmaf(wc, (x1 - mu) * isig, bc);
        float l0 = log10f(fmaf(y0, y0, 1e-6f));
        float l1 = log10f(fmaf(y1, y1, 1e-6f));
        out[b * 4096 + idx] = l0 * (1.0f - fr) + l1 * fr;
    }
}

// ---------------------------------------------------------------------------
// Fallback (R2 VALU path) if ws_size is too small for the B table.
// ---------------------------------------------------------------------------
__global__ __launch_bounds__(512, 2)
void fse_main_valu(const float* __restrict__ wav,
                   const float* __restrict__ low_hz_,
                   const float* __restrict__ band_hz_,
                   const float* __restrict__ ln_w,
                   const float* __restrict__ ln_b,
                   float* __restrict__ out)
{
    __shared__ float  xp[16400];
    __shared__ float2 Xs[8][204];
    __shared__ float  mags[8][204];
    __shared__ float  fbuf[64 * 101];
    __shared__ float  fctr[64], finv[64];
    __shared__ int    fks[64], fke[64];
    __shared__ float  red[8];
    __shared__ float  stats[2];

    const int b    = blockIdx.x;
    const int tid  = threadIdx.x;
    const int w    = tid >> 6;
    const int lane = tid & 63;
    const float* __restrict__ x = wav + b * 16000;

    for (int i = tid; i < 16400; i += BLOCK) {
        int p = i - 200;
        p = (p < 0) ? -p : p;
        p = (p > 15999) ? (31998 - p) : p;
        xp[i] = x[p];
    }
    if (tid < 64) {
        float lo = 50.0f + fabsf(low_hz_[tid]);
        float hi = lo + 50.0f + fabsf(band_hz_[tid]);
        hi = fminf(fmaxf(hi, 50.0f), 8000.0f);
        float ctr = 0.5f * (lo + hi);
        float hbw = 0.5f * (hi - lo);
        int ks = (int)ceilf(lo * 0.025f);
        if (ks < 0) ks = 0;
        while (40.0f * (float)ks < lo) ++ks;
        while (ks > 0 && 40.0f * (float)(ks - 1) >= lo) --ks;
        int ke = (int)floorf(hi * 0.025f);
        if (ke > 200) ke = 200;
        while (40.0f * (float)ke > hi) --ke;
        while (ke < 200 && 40.0f * (float)(ke + 1) <= hi) ++ke;
        fctr[tid] = ctr;
        finv[tid] = (hbw > 0.0f) ? (1.0f / hbw) : 0.0f;
        fks[tid]  = ks;
        fke[tid]  = ke;
    }
    __syncthreads();

    const float cctr = fctr[lane];
    const float cinv = finv[lane];
    const int   cks  = fks[lane];
    const int   cke  = fke[lane];

    float reX[4][13], imX[4][13];
    const float2* __restrict__ xp2 = (const float2*)xp;
    float c0[4], s0[4], c1[4], s1[4], cd[4], sd[4];
    #pragma unroll
    for (int m = 0; m < 4; ++m) {
        const int k = m * 64 + lane;
        const float th = -0.015707963267948966f * (float)k;
        sincosf(th, &s1[m], &c1[m]);
        sincosf(th + th, &sd[m], &cd[m]);
        c0[m] = 1.0f; s0[m] = 0.0f;
        #pragma unroll
        for (int j = 0; j < 13; ++j) { reX[m][j] = 0.0f; imX[m][j] = 0.0f; }
    }
    const int o12 = (w < 5) ? 640 * 12 : 0;
    int ib = 80 * w;
    #pragma unroll 2
    for (int h = 0; h < 200; ++h) {
        #pragma unroll
        for (int j = 0; j < 13; ++j) {
            const int off = (j == 12) ? o12 : 640 * j;
            float2 f = xp2[ib + off];
            #pragma unroll
            for (int m = 0; m < 4; ++m) {
                reX[m][j] = fmaf(f.x, c0[m], reX[m][j]);
                imX[m][j] = fmaf(f.x, s0[m], imX[m][j]);
                reX[m][j] = fmaf(f.y, c1[m], reX[m][j]);
                imX[m][j] = fmaf(f.y, s1[m], imX[m][j]);
            }
        }
        #pragma unroll
        for (int m = 0; m < 4; ++m) {
            float nc0 = fmaf(c0[m], cd[m], -(s0[m] * sd[m]));
            float ns0 = fmaf(s0[m], cd[m],  (c0[m] * sd[m]));
            float nc1 = fmaf(c1[m], cd[m], -(s1[m] * sd[m]));
            float ns1 = fmaf(s1[m], cd[m],  (c1[m] * sd[m]));
            c0[m] = nc0; s0[m] = ns0; c1[m] = nc1; s1[m] = ns1;
        }
        ++ib;
    }

    float2* __restrict__ myX   = &Xs[w][0];
    float*  __restrict__ mymag = &mags[w][0];
    for (int j = 0; j < 13; ++j) {
        const int t = w + 8 * j;
        if (t > 100) break;
        #pragma unroll
        for (int m = 0; m < 4; ++m) {
            const int k = m * 64 + lane;
            if (k < 202) myX[k] = make_float2(reX[m][j], imX[m][j]);
        }
        asm volatile("s_waitcnt lgkmcnt(0)" ::: "memory");
        #pragma unroll
        for (int m = 0; m < 4; ++m) {
            const int k = m * 64 + lane;
            if (k <= 200) {
                float2 xm = (k == 0) ? myX[1] : myX[k - 1];
                float imm = (k == 0) ? -xm.y : xm.y;
                float2 xq = myX[k + 1];
                float rw = 0.5f * reX[m][j] - 0.25f * (xm.x + xq.x);
                float iw = 0.5f * imX[m][j] - 0.25f * (imm  + xq.y);
                mymag[k] = sqrtf(rw * rw + iw * iw);
            }
        }
        asm volatile("s_waitcnt lgkmcnt(0)" ::: "memory");
        float acc = 0.0f;
        for (int k = cks; k <= cke; ++k) {
            float resp = 1.0f - fabsf(40.0f * (float)k - cctr) * cinv;
            acc = fmaf(resp, mymag[k], acc);
        }
        fbuf[lane * 101 + t] = acc;
    }
    __syncthreads();

    float s = 0.0f;
    for (int i = tid; i < 6464; i += BLOCK) s += fbuf[i];
    #pragma unroll
    for (int off = 32; off > 0; off >>= 1) s += __shfl_down(s, off, 64);
    if (lane == 0) red[w] = s;
    __syncthreads();
    if (tid == 0) {
        float tsum = 0.0f;
        for (int i = 0; i < 8; ++i) tsum += red[i];
        stats[0] = tsum * (1.0f / 6464.0f);
    }
    __syncthreads();
    const float mu = stats[0];
    float v = 0.0f;
    for (int i = tid; i < 6464; i += BLOCK) { float d = fbuf[i] - mu; v = fmaf(d, d, v); }
    #pragma unroll
    for (int off = 32; off > 0; off >>= 1) v += __shfl_down(v, off, 64);
    if (lane == 0) red[w] = v;
    __syncthreads();
    if (tid == 0) {
        float tsum = 0.0f;
        for (int i = 0; i < 8; ++i) tsum += red[i];
        stats[1] = tsum * (1.0f / 6464.0f);
    }
    __syncthreads();
    const float var  = stats[1];
    const float isig = 1.0f / sqrtf(var + 1e-5f);

    for (int idx = tid; idx < 4096; idx += BLOCK) {
        const int to = idx >> 6;
        const int c  = idx & 63;
        float pos = ((float)to + 0.5f) * 1.578125f - 0.5f;
        pos = fminf(fmaxf(pos, 0.0f), 100.0f);
        int i0 = (int)floorf(pos);
        int i1 = i0 + 1; if (i1 > 100) i1 = 100;
        float fr = pos - (float)i0;
        float wc = ln_w[c], bc = ln_b[c];
        float x0 = fbuf[c * 101 + i0];
        float x1 = fbuf[c * 101 + i1];
        float y0 = fmaf(wc, (x0 - mu) * isig, bc);
        float y1 = fmaf(wc, (x1 - mu) * isig, bc);
        float l0 = log10f(fmaf(y0, y0, 1e-6f));
        float l1 = log10f(fmaf(y1, y1, 1e-6f));
        out[b * 4096 + idx] = l0 * (1.0f - fr) + l1 * fr;
    }
}

extern "C" void kernel_launch(void* const* d_in, const int* in_sizes, int n_in,
                              void* d_out, int out_size, void* d_ws, size_t ws_size,
                              hipStream_t stream)
{
    const float* wav = (const float*)d_in[0];
    const float* lo  = (const float*)d_in[1];
    const float* bd  = (const float*)d_in[2];
    const float* lw  = (const float*)d_in[3];
    const float* lb  = (const float*)d_in[4];
    float* out = (float*)d_out;

    fse_filters<<<(64 * 201 + 255) / 256, 256, 0, stream>>>(lo, bd, out + 1024 * 4096);

    const size_t BNEED = (size_t)372736 * sizeof(unsigned short); // 745472 B
    if (ws_size >= BNEED) {
        unsigned short* Bts = (unsigned short*)d_ws;
        fse_setup_B<<<(372736 + 255) / 256, 256, 0, stream>>>(Bts);
        fse_main_mfma<<<1024, BLOCK, 0, stream>>>(wav, lo, bd, lw, lb, Bts, out);
    } else {
        fse_main_valu<<<1024, BLOCK, 0, stream>>>(wav, lo, bd, lw, lb, out);
    }
}